// Round 1
// baseline (1241.449 us; speedup 1.0000x reference)
//
#include <hip/hip_runtime.h>
#include <cstddef>

#define N_TOK 4096
#define M_DIM 1024
#define APER  256
constexpr float FMAXV = 3.4028235e38f;

// ---------------------------------------------------------------------------
// C[M x N] = alpha * A[M x Kd] @ B[Kd x N]   (all row-major)
// 64x64 tile, BK=16, 256 threads, 4x4 micro-tile per thread.
// ---------------------------------------------------------------------------
__global__ __launch_bounds__(256) void gemm_nn(const float* __restrict__ A,
                                               const float* __restrict__ B,
                                               float* __restrict__ C,
                                               int M, int N, int Kd, float alpha) {
    __shared__ float As[16][64]; // As[k][m]
    __shared__ float Bs[16][64]; // Bs[k][n]
    const int row0 = blockIdx.y * 64;
    const int col0 = blockIdx.x * 64;
    const int t  = threadIdx.x;
    const int tx = t & 15;
    const int ty = t >> 4;
    float acc[4][4] = {};

    for (int k0 = 0; k0 < Kd; k0 += 16) {
        // A tile 64x16 -> As[k][m] (transposed store)
        {
            const int r  = t >> 2;
            const int kv = (t & 3) * 4;
            const float4 av = *reinterpret_cast<const float4*>(&A[(row0 + r) * Kd + k0 + kv]);
            As[kv + 0][r] = av.x; As[kv + 1][r] = av.y;
            As[kv + 2][r] = av.z; As[kv + 3][r] = av.w;
        }
        // B tile 16x64 -> Bs[k][n] (direct)
        {
            const int kr = t >> 4;
            const int nv = (t & 15) * 4;
            *reinterpret_cast<float4*>(&Bs[kr][nv]) =
                *reinterpret_cast<const float4*>(&B[(k0 + kr) * N + col0 + nv]);
        }
        __syncthreads();
#pragma unroll
        for (int k = 0; k < 16; ++k) {
            const float4 a4 = *reinterpret_cast<const float4*>(&As[k][ty * 4]);
            const float4 b4 = *reinterpret_cast<const float4*>(&Bs[k][tx * 4]);
            const float a[4] = {a4.x, a4.y, a4.z, a4.w};
            const float b[4] = {b4.x, b4.y, b4.z, b4.w};
#pragma unroll
            for (int i = 0; i < 4; ++i)
#pragma unroll
                for (int j = 0; j < 4; ++j) acc[i][j] += a[i] * b[j];
        }
        __syncthreads();
    }
#pragma unroll
    for (int i = 0; i < 4; ++i) {
        const int r = row0 + ty * 4 + i;
        float4 o;
        o.x = alpha * acc[i][0]; o.y = alpha * acc[i][1];
        o.z = alpha * acc[i][2]; o.w = alpha * acc[i][3];
        *reinterpret_cast<float4*>(&C[r * N + col0 + tx * 4]) = o;
    }
}

// ---------------------------------------------------------------------------
// logits: C[M x N] = A[M x Kd] @ B[N x Kd]^T  (Q @ K^T), skipping tiles that
// are fully masked by the aperture (j - i <= APER never read by softmax).
// ---------------------------------------------------------------------------
__global__ __launch_bounds__(256) void gemm_nt(const float* __restrict__ A,
                                               const float* __restrict__ B,
                                               float* __restrict__ C,
                                               int M, int N, int Kd) {
    const int row0 = blockIdx.y * 64;
    const int col0 = blockIdx.x * 64;
    if (col0 + 63 <= row0 + APER) return; // fully masked tile: never read

    __shared__ float As[16][64]; // As[k][i]
    __shared__ float Bs[16][64]; // Bs[k][j]
    const int t  = threadIdx.x;
    const int tx = t & 15;
    const int ty = t >> 4;
    float acc[4][4] = {};

    for (int k0 = 0; k0 < Kd; k0 += 16) {
        const int r  = t >> 2;
        const int kv = (t & 3) * 4;
        {
            const float4 av = *reinterpret_cast<const float4*>(&A[(row0 + r) * Kd + k0 + kv]);
            As[kv + 0][r] = av.x; As[kv + 1][r] = av.y;
            As[kv + 2][r] = av.z; As[kv + 3][r] = av.w;
        }
        {
            const float4 bv = *reinterpret_cast<const float4*>(&B[(col0 + r) * Kd + k0 + kv]);
            Bs[kv + 0][r] = bv.x; Bs[kv + 1][r] = bv.y;
            Bs[kv + 2][r] = bv.z; Bs[kv + 3][r] = bv.w;
        }
        __syncthreads();
#pragma unroll
        for (int k = 0; k < 16; ++k) {
            const float4 a4 = *reinterpret_cast<const float4*>(&As[k][ty * 4]);
            const float4 b4 = *reinterpret_cast<const float4*>(&Bs[k][tx * 4]);
            const float a[4] = {a4.x, a4.y, a4.z, a4.w};
            const float b[4] = {b4.x, b4.y, b4.z, b4.w};
#pragma unroll
            for (int i = 0; i < 4; ++i)
#pragma unroll
                for (int j = 0; j < 4; ++j) acc[i][j] += a[i] * b[j];
        }
        __syncthreads();
    }
#pragma unroll
    for (int i = 0; i < 4; ++i) {
        const int r = row0 + ty * 4 + i;
        float4 o;
        o.x = acc[i][0]; o.y = acc[i][1]; o.z = acc[i][2]; o.w = acc[i][3];
        *reinterpret_cast<float4*>(&C[r * N + col0 + tx * 4]) = o;
    }
}

// ---------------------------------------------------------------------------
// In-place masked softmax over each row of att (4096 x 4096).
// Kept entries: j > i + APER. Rows with no kept entries -> uniform 1/N.
// ---------------------------------------------------------------------------
__global__ __launch_bounds__(256) void softmax_mask(float* __restrict__ att) {
    const int i = blockIdx.x;
    const int t = threadIdx.x;
    float* row = att + (size_t)i * N_TOK;
    const int jstart = i + APER + 1;

    if (jstart >= N_TOK) { // all masked -> exact uniform
        const float u = 1.0f / (float)N_TOK;
        for (int j = t; j < N_TOK; j += 256) row[j] = u;
        return;
    }

    __shared__ float smax[4];
    __shared__ float ssum[4];
    const int wid = t >> 6, lid = t & 63;

    // 1) row max over kept entries
    float lmax = -FMAXV;
    for (int j = jstart + t; j < N_TOK; j += 256) lmax = fmaxf(lmax, row[j]);
#pragma unroll
    for (int off = 32; off > 0; off >>= 1) lmax = fmaxf(lmax, __shfl_down(lmax, off, 64));
    if (lid == 0) smax[wid] = lmax;
    __syncthreads();
    const float rmax = fmaxf(fmaxf(smax[0], smax[1]), fmaxf(smax[2], smax[3]));

    // 2) exp in place + sum
    float lsum = 0.0f;
    for (int j = jstart + t; j < N_TOK; j += 256) {
        const float e = __expf(row[j] - rmax);
        row[j] = e;
        lsum += e;
    }
#pragma unroll
    for (int off = 32; off > 0; off >>= 1) lsum += __shfl_down(lsum, off, 64);
    if (lid == 0) ssum[wid] = lsum;
    __syncthreads();
    const float rsum = ssum[0] + ssum[1] + ssum[2] + ssum[3];
    const float inv  = 1.0f / rsum;

    // 3) normalize kept, zero masked
    for (int j = t; j < jstart; j += 256) row[j] = 0.0f;
    for (int j = jstart + t; j < N_TOK; j += 256) row[j] *= inv;
}

// ---------------------------------------------------------------------------
// yt = att^T @ V : C[Mo x N], C[r][c] = sum_i A[i][r] * B[i][c]
// A is Kd x Mo (att, lda=Mo), B is Kd x N (V). Skips all-zero k-blocks.
// ---------------------------------------------------------------------------
__global__ __launch_bounds__(256) void gemm_tn(const float* __restrict__ A,
                                               const float* __restrict__ B,
                                               float* __restrict__ C,
                                               int Mo, int N, int Kd) {
    __shared__ float As[16][64]; // As[k][r] — direct (A already K-major)
    __shared__ float Bs[16][64]; // Bs[k][c]
    const int row0 = blockIdx.y * 64;
    const int col0 = blockIdx.x * 64;
    const int t  = threadIdx.x;
    const int tx = t & 15;
    const int ty = t >> 4;
    float acc[4][4] = {};
    const int uniformStart = N_TOK - APER - 1; // 3839: rows >= this are uniform

    for (int k0 = 0; k0 < Kd; k0 += 16) {
        // att[i][r] == 0 for r <= i+APER when i < uniformStart: skip zero blocks
        if ((row0 + 63 <= k0 + APER) && (k0 + 15 < uniformStart)) continue;
        {
            const int kr = t >> 4;
            const int rv = (t & 15) * 4;
            *reinterpret_cast<float4*>(&As[kr][rv]) =
                *reinterpret_cast<const float4*>(&A[(size_t)(k0 + kr) * Mo + row0 + rv]);
            *reinterpret_cast<float4*>(&Bs[kr][rv]) =
                *reinterpret_cast<const float4*>(&B[(k0 + kr) * N + col0 + rv]);
        }
        __syncthreads();
#pragma unroll
        for (int k = 0; k < 16; ++k) {
            const float4 a4 = *reinterpret_cast<const float4*>(&As[k][ty * 4]);
            const float4 b4 = *reinterpret_cast<const float4*>(&Bs[k][tx * 4]);
            const float a[4] = {a4.x, a4.y, a4.z, a4.w};
            const float b[4] = {b4.x, b4.y, b4.z, b4.w};
#pragma unroll
            for (int i = 0; i < 4; ++i)
#pragma unroll
                for (int j = 0; j < 4; ++j) acc[i][j] += a[i] * b[j];
        }
        __syncthreads();
    }
#pragma unroll
    for (int i = 0; i < 4; ++i) {
        const int r = row0 + ty * 4 + i;
        float4 o;
        o.x = acc[i][0]; o.y = acc[i][1]; o.z = acc[i][2]; o.w = acc[i][3];
        *reinterpret_cast<float4*>(&C[r * N + col0 + tx * 4]) = o;
    }
}

extern "C" void kernel_launch(void* const* d_in, const int* in_sizes, int n_in,
                              void* d_out, int out_size, void* d_ws, size_t ws_size,
                              hipStream_t stream) {
    const float* x    = (const float*)d_in[0];
    const float* WK   = (const float*)d_in[1];
    const float* WQ   = (const float*)d_in[2];
    const float* WV   = (const float*)d_in[3];
    const float* Wout = (const float*)d_in[4];

    float* y   = (float*)d_out;                        // 4096 x 1024
    float* att = y + (size_t)N_TOK * M_DIM;            // 4096 x 4096

    float* Kb = (float*)d_ws;                          // 4096 x 1024
    float* Qb = Kb + (size_t)N_TOK * M_DIM;            // 4096 x 1024
    float* Vb = Qb + (size_t)N_TOK * M_DIM;            // 4096 x 1024
    float* yt = Qb;                                    // reuse Q after logits

    const dim3 blk(256);
    const dim3 gProj(M_DIM / 64, N_TOK / 64);          // 16 x 64
    const dim3 gLog(N_TOK / 64, N_TOK / 64);           // 64 x 64

    gemm_nn<<<gProj, blk, 0, stream>>>(x, WK, Kb, N_TOK, M_DIM, M_DIM, 1.0f);
    gemm_nn<<<gProj, blk, 0, stream>>>(x, WQ, Qb, N_TOK, M_DIM, M_DIM, 0.06f);
    gemm_nn<<<gProj, blk, 0, stream>>>(x, WV, Vb, N_TOK, M_DIM, M_DIM, 1.0f);

    gemm_nt<<<gLog, blk, 0, stream>>>(Qb, Kb, att, N_TOK, N_TOK, M_DIM);
    softmax_mask<<<dim3(N_TOK), blk, 0, stream>>>(att);
    gemm_tn<<<gProj, blk, 0, stream>>>(att, Vb, yt, N_TOK, M_DIM, N_TOK);

    gemm_nn<<<gProj, blk, 0, stream>>>(yt, Wout, y, N_TOK, M_DIM, M_DIM, 1.0f);
}

// Round 2
// 401.115 us; speedup vs baseline: 3.0950x; 3.0950x over previous
//
#include <hip/hip_runtime.h>
#include <cstdint>
#include <cstddef>

#define N_TOK 4096
#define M_DIM 1024
#define APER  256
constexpr float FMAXV = 3.4028235e38f;

typedef __attribute__((ext_vector_type(8))) short short8;
typedef __attribute__((ext_vector_type(4))) float float4_t;

__device__ __forceinline__ unsigned short f2bf(float x) {
    union { float f; uint32_t u; } v; v.f = x;
    uint32_t u = v.u;
    u += 0x7FFFu + ((u >> 16) & 1u);   // round-to-nearest-even
    return (unsigned short)(u >> 16);
}

__device__ __forceinline__ void gload16(const void* g, void* l) {
    __builtin_amdgcn_global_load_lds(
        (const __attribute__((address_space(1))) void*)g,
        (__attribute__((address_space(3))) void*)l, 16, 0, 0);
}

// ---------------------------------------------------------------------------
// cast fp32 -> bf16, same layout. n must be multiple of 4.
// ---------------------------------------------------------------------------
__global__ __launch_bounds__(256) void cast_bf16(const float* __restrict__ src,
                                                 unsigned short* __restrict__ dst, int n) {
    const int i = (blockIdx.x * 256 + threadIdx.x) * 4;
    if (i >= n) return;
    const float4 v = *reinterpret_cast<const float4*>(&src[i]);
    ushort4 o;
    o.x = f2bf(v.x); o.y = f2bf(v.y); o.z = f2bf(v.z); o.w = f2bf(v.w);
    *reinterpret_cast<ushort4*>(&dst[i]) = o;
}

// ---------------------------------------------------------------------------
// transpose + cast: src fp32 [R x C] -> dst bf16 [C x R]
// ---------------------------------------------------------------------------
__global__ __launch_bounds__(256) void transpose_cast_f32(const float* __restrict__ src,
                                                          unsigned short* __restrict__ dst,
                                                          int R, int C) {
    __shared__ unsigned short tile[32][33];
    const int c0 = blockIdx.x * 32, r0 = blockIdx.y * 32;
    const int tx = threadIdx.x & 31, ty = threadIdx.x >> 5; // ty 0..7
#pragma unroll
    for (int i = ty; i < 32; i += 8)
        tile[i][tx] = f2bf(src[(size_t)(r0 + i) * C + c0 + tx]);
    __syncthreads();
#pragma unroll
    for (int i = ty; i < 32; i += 8)
        dst[(size_t)(c0 + i) * R + r0 + tx] = tile[tx][i];
}

// transpose bf16 [R x C] -> bf16 [C x R]
__global__ __launch_bounds__(256) void transpose_bf16(const unsigned short* __restrict__ src,
                                                      unsigned short* __restrict__ dst,
                                                      int R, int C) {
    __shared__ unsigned short tile[32][33];
    const int c0 = blockIdx.x * 32, r0 = blockIdx.y * 32;
    const int tx = threadIdx.x & 31, ty = threadIdx.x >> 5;
#pragma unroll
    for (int i = ty; i < 32; i += 8)
        tile[i][tx] = src[(size_t)(r0 + i) * C + c0 + tx];
    __syncthreads();
#pragma unroll
    for (int i = ty; i < 32; i += 8)
        dst[(size_t)(c0 + i) * R + r0 + tx] = tile[tx][i];
}

// ---------------------------------------------------------------------------
// MFMA NT GEMM: C[M x N] = alpha * A[M x K] (bf16 rowmajor) @ B[N x K]^T (bf16)
// 128x128 tile, BK=32, 256 threads = 4 waves, each wave 64x64 (4x4 MFMA 16x16x32).
// SKIP: 0 none; 1 logits aperture tile-skip; 2 att^T zero-k-block skip.
// Outputs: Cf (fp32) and/or Cb (bf16), either may be null.
// ---------------------------------------------------------------------------
template <int SKIP>
__global__ __launch_bounds__(256) void mfma_nt(const unsigned short* __restrict__ A,
                                               const unsigned short* __restrict__ B,
                                               float* __restrict__ Cf,
                                               unsigned short* __restrict__ Cb,
                                               int M, int N, int K, float alpha) {
    const int row0 = blockIdx.y * 128;
    const int col0 = blockIdx.x * 128;
    if (SKIP == 1 && col0 + 127 <= row0 + APER) return; // fully masked logits tile

    __shared__ unsigned short Asb[128 * 32];
    __shared__ unsigned short Bsb[128 * 32];

    const int t    = threadIdx.x;
    const int w    = t >> 6;       // wave 0..3
    const int lane = t & 63;
    const int wr   = (w >> 1) * 64; // wave's row offset inside 128-tile
    const int wc   = (w & 1) * 64;  // wave's col offset

    float4_t acc[4][4] = {};

    // staging: wave w loads chunks 2w, 2w+1 (16 rows x 32 k each) for A and B.
    // chunk layout == hardware layout: lds base + lane*16B, lane = q*4+p,
    // row = c*16 + q, k-off = p*8.
    const int sr = lane >> 2;          // 0..15 row within chunk
    const int sk = (lane & 3) * 8;     // 0,8,16,24

    for (int k0 = 0; k0 < K; k0 += 32) {
        if (SKIP == 2) {
            // A = att^T: column i nonzero only if i <= row-APER-1 (row<=row0+127)
            // or i >= N_TOK-APER-1 (uniform rows)
            if ((k0 > row0 + 127 - APER - 1) && (k0 + 31 < N_TOK - APER - 1)) continue;
        }
#pragma unroll
        for (int cc = 0; cc < 2; ++cc) {
            const int c = 2 * w + cc;
            const int rr = c * 16 + sr;
            gload16(&A[(size_t)(row0 + rr) * K + k0 + sk], &Asb[c * 512]);
            gload16(&B[(size_t)(col0 + rr) * K + k0 + sk], &Bsb[c * 512]);
        }
        __syncthreads();

        short8 af[4], bf[4];
#pragma unroll
        for (int i = 0; i < 4; ++i)
            af[i] = *reinterpret_cast<const short8*>(
                &Asb[(wr + i * 16 + (lane & 15)) * 32 + (lane >> 4) * 8]);
#pragma unroll
        for (int j = 0; j < 4; ++j)
            bf[j] = *reinterpret_cast<const short8*>(
                &Bsb[(wc + j * 16 + (lane & 15)) * 32 + (lane >> 4) * 8]);
#pragma unroll
        for (int i = 0; i < 4; ++i)
#pragma unroll
            for (int j = 0; j < 4; ++j)
                acc[i][j] = __builtin_amdgcn_mfma_f32_16x16x32_bf16(af[i], bf[j], acc[i][j], 0, 0, 0);
        __syncthreads();
    }

    // epilogue: C/D layout col=lane&15, row=(lane>>4)*4+reg  [m89/m91 verified]
    const int crow  = row0 + wr + (lane >> 4) * 4;
    const int ccol  = col0 + wc + (lane & 15);
#pragma unroll
    for (int i = 0; i < 4; ++i) {
#pragma unroll
        for (int j = 0; j < 4; ++j) {
#pragma unroll
            for (int r = 0; r < 4; ++r) {
                const int gr = crow + i * 16 + r;
                const int gc = ccol + j * 16;
                const float v = alpha * acc[i][j][r];
                if (Cf) Cf[(size_t)gr * N + gc] = v;
                if (Cb) Cb[(size_t)gr * N + gc] = f2bf(v);
            }
        }
    }
}

// ---------------------------------------------------------------------------
// In-place masked softmax over rows of att (fp32 4096x4096).
// Kept entries: j > i + APER. Rows with none -> exact uniform 1/N.
// ---------------------------------------------------------------------------
__global__ __launch_bounds__(256) void softmax_mask(float* __restrict__ att) {
    const int i = blockIdx.x;
    const int t = threadIdx.x;
    float* row = att + (size_t)i * N_TOK;
    const int jstart = i + APER + 1;

    if (jstart >= N_TOK) {
        const float u = 1.0f / (float)N_TOK;
        for (int j = t; j < N_TOK; j += 256) row[j] = u;
        return;
    }

    __shared__ float smax[4];
    __shared__ float ssum[4];
    const int wid = t >> 6, lid = t & 63;

    float lmax = -FMAXV;
    for (int j = jstart + t; j < N_TOK; j += 256) lmax = fmaxf(lmax, row[j]);
#pragma unroll
    for (int off = 32; off > 0; off >>= 1) lmax = fmaxf(lmax, __shfl_down(lmax, off, 64));
    if (lid == 0) smax[wid] = lmax;
    __syncthreads();
    const float rmax = fmaxf(fmaxf(smax[0], smax[1]), fmaxf(smax[2], smax[3]));

    float lsum = 0.0f;
    for (int j = jstart + t; j < N_TOK; j += 256) {
        const float e = __expf(row[j] - rmax);
        row[j] = e;
        lsum += e;
    }
#pragma unroll
    for (int off = 32; off > 0; off >>= 1) lsum += __shfl_down(lsum, off, 64);
    if (lid == 0) ssum[wid] = lsum;
    __syncthreads();
    const float rsum = ssum[0] + ssum[1] + ssum[2] + ssum[3];
    const float inv  = 1.0f / rsum;

    for (int j = t; j < jstart; j += 256) row[j] = 0.0f;
    for (int j = jstart + t; j < N_TOK; j += 256) row[j] *= inv;
}

extern "C" void kernel_launch(void* const* d_in, const int* in_sizes, int n_in,
                              void* d_out, int out_size, void* d_ws, size_t ws_size,
                              hipStream_t stream) {
    const float* x    = (const float*)d_in[0];
    const float* WK   = (const float*)d_in[1];
    const float* WQ   = (const float*)d_in[2];
    const float* WV   = (const float*)d_in[3];
    const float* Wout = (const float*)d_in[4];

    float* y   = (float*)d_out;                  // 4096 x 1024 fp32
    float* att = y + (size_t)N_TOK * M_DIM;      // 4096 x 4096 fp32

    // workspace carve-up (bf16 buffers, sizes in elements)
    unsigned short* p = (unsigned short*)d_ws;
    unsigned short* xb    = p; p += (size_t)N_TOK * M_DIM;  // 8 MB
    unsigned short* WKt   = p; p += (size_t)M_DIM * M_DIM;  // 2 MB
    unsigned short* WQt   = p; p += (size_t)M_DIM * M_DIM;
    unsigned short* WVt   = p; p += (size_t)M_DIM * M_DIM;
    unsigned short* Woutt = p; p += (size_t)M_DIM * M_DIM;
    unsigned short* Kb    = p; p += (size_t)N_TOK * M_DIM;  // 8 MB
    unsigned short* Qb    = p; p += (size_t)N_TOK * M_DIM;  // 8 MB
    unsigned short* Vb    = p; p += (size_t)N_TOK * M_DIM;  // 8 MB
    unsigned short* attT  = p; p += (size_t)N_TOK * N_TOK;  // 32 MB
    unsigned short* Vt    = xb;  // reuse: xb dead after projections
    unsigned short* ytb   = Qb;  // reuse: Qb dead after logits

    const dim3 blk(256);

    // 1) casts / transposes of inputs
    cast_bf16<<<dim3((N_TOK * M_DIM) / 1024), blk, 0, stream>>>(x, xb, N_TOK * M_DIM);
    const dim3 gW(M_DIM / 32, M_DIM / 32);
    transpose_cast_f32<<<gW, blk, 0, stream>>>(WK,   WKt,   M_DIM, M_DIM);
    transpose_cast_f32<<<gW, blk, 0, stream>>>(WQ,   WQt,   M_DIM, M_DIM);
    transpose_cast_f32<<<gW, blk, 0, stream>>>(WV,   WVt,   M_DIM, M_DIM);
    transpose_cast_f32<<<gW, blk, 0, stream>>>(Wout, Woutt, M_DIM, M_DIM);

    // 2) projections (NT: B = W^T)
    const dim3 gProj(M_DIM / 128, N_TOK / 128);  // (8, 32)
    mfma_nt<0><<<gProj, blk, 0, stream>>>(xb, WKt, nullptr, Kb, N_TOK, M_DIM, M_DIM, 1.0f);
    mfma_nt<0><<<gProj, blk, 0, stream>>>(xb, WQt, nullptr, Qb, N_TOK, M_DIM, M_DIM, 0.06f);
    mfma_nt<0><<<gProj, blk, 0, stream>>>(xb, WVt, nullptr, Vb, N_TOK, M_DIM, M_DIM, 1.0f);

    // 3) logits = Q @ K^T (fp32 out, aperture tile-skip)
    const dim3 gLog(N_TOK / 128, N_TOK / 128);   // (32, 32)
    mfma_nt<1><<<gLog, blk, 0, stream>>>(Qb, Kb, att, nullptr, N_TOK, N_TOK, M_DIM, 1.0f);

    // 4) masked softmax in place
    softmax_mask<<<dim3(N_TOK), blk, 0, stream>>>(att);

    // 5) att^T (bf16) and V^T (bf16)
    transpose_cast_f32<<<dim3(N_TOK / 32, N_TOK / 32), blk, 0, stream>>>(att, attT, N_TOK, N_TOK);
    transpose_bf16<<<dim3(M_DIM / 32, N_TOK / 32), blk, 0, stream>>>(Vb, Vt, N_TOK, M_DIM);

    // 6) yt = att^T @ V  (NT: A = att^T rowmajor, B = V^T rowmajor; zero-k skip)
    mfma_nt<2><<<gProj, blk, 0, stream>>>(attT, Vt, nullptr, ytb, N_TOK, M_DIM, N_TOK, 1.0f);

    // 7) y = yt @ Wout (NT: B = Wout^T)
    mfma_nt<0><<<gProj, blk, 0, stream>>>(ytb, Woutt, y, nullptr, N_TOK, M_DIM, M_DIM, 1.0f);
}

// Round 3
// 310.970 us; speedup vs baseline: 3.9922x; 1.2899x over previous
//
#include <hip/hip_runtime.h>
#include <cstdint>
#include <cstddef>

#define N_TOK 4096
#define M_DIM 1024
#define APER  256
constexpr float FMAXV = 3.4028235e38f;

typedef __attribute__((ext_vector_type(8))) short short8;
typedef __attribute__((ext_vector_type(4))) float float4_t;

__device__ __forceinline__ unsigned short f2bf(float x) {
    union { float f; uint32_t u; } v; v.f = x;
    uint32_t u = v.u;
    u += 0x7FFFu + ((u >> 16) & 1u);   // round-to-nearest-even
    return (unsigned short)(u >> 16);
}

__device__ __forceinline__ void gload16(const void* g, void* l) {
    __builtin_amdgcn_global_load_lds(
        (const __attribute__((address_space(1))) void*)g,
        (__attribute__((address_space(3))) void*)l, 16, 0, 0);
}

// ---------------------------------------------------------------------------
// cast fp32 -> bf16, same layout.
// ---------------------------------------------------------------------------
__global__ __launch_bounds__(256) void cast_bf16(const float* __restrict__ src,
                                                 unsigned short* __restrict__ dst, int n) {
    const int i = (blockIdx.x * 256 + threadIdx.x) * 4;
    if (i >= n) return;
    const float4 v = *reinterpret_cast<const float4*>(&src[i]);
    ushort4 o;
    o.x = f2bf(v.x); o.y = f2bf(v.y); o.z = f2bf(v.z); o.w = f2bf(v.w);
    *reinterpret_cast<ushort4*>(&dst[i]) = o;
}

// ---------------------------------------------------------------------------
// fused transpose+cast of the 4 weight matrices (1024x1024 fp32 -> bf16^T)
// ---------------------------------------------------------------------------
__global__ __launch_bounds__(256) void wtrans(const float* __restrict__ W0, const float* __restrict__ W1,
                                              const float* __restrict__ W2, const float* __restrict__ W3,
                                              unsigned short* __restrict__ D0, unsigned short* __restrict__ D1,
                                              unsigned short* __restrict__ D2, unsigned short* __restrict__ D3) {
    const int z = blockIdx.z;
    const float* src = z == 0 ? W0 : (z == 1 ? W1 : (z == 2 ? W2 : W3));
    unsigned short* dst = z == 0 ? D0 : (z == 1 ? D1 : (z == 2 ? D2 : D3));
    __shared__ unsigned short tile[32][33];
    const int c0 = blockIdx.x * 32, r0 = blockIdx.y * 32;
    const int tx = threadIdx.x & 31, ty = threadIdx.x >> 5;
#pragma unroll
    for (int i = ty; i < 32; i += 8)
        tile[i][tx] = f2bf(src[(size_t)(r0 + i) * M_DIM + c0 + tx]);
    __syncthreads();
#pragma unroll
    for (int i = ty; i < 32; i += 8)
        dst[(size_t)(c0 + i) * M_DIM + r0 + tx] = tile[tx][i];
}

// transpose bf16 [R x C] -> bf16 [C x R]
__global__ __launch_bounds__(256) void transpose_bf16(const unsigned short* __restrict__ src,
                                                      unsigned short* __restrict__ dst,
                                                      int R, int C) {
    __shared__ unsigned short tile[32][33];
    const int c0 = blockIdx.x * 32, r0 = blockIdx.y * 32;
    const int tx = threadIdx.x & 31, ty = threadIdx.x >> 5;
#pragma unroll
    for (int i = ty; i < 32; i += 8)
        tile[i][tx] = src[(size_t)(r0 + i) * C + c0 + tx];
    __syncthreads();
#pragma unroll
    for (int i = ty; i < 32; i += 8)
        dst[(size_t)(c0 + i) * R + r0 + tx] = tile[tx][i];
}

// ---------------------------------------------------------------------------
// Fused QKV: C_seg[4096x1024] = alpha_seg * xb @ Wseg^T, seg from blockIdx.x.
// 128x128 tile, BK=32, XOR-swizzled LDS. Grid (24, 32) = 768 blocks.
// ---------------------------------------------------------------------------
__global__ __launch_bounds__(256) void mfma_qkv(const unsigned short* __restrict__ xb,
                                                const unsigned short* __restrict__ WKt,
                                                const unsigned short* __restrict__ WQt,
                                                const unsigned short* __restrict__ WVt,
                                                unsigned short* __restrict__ Kb,
                                                unsigned short* __restrict__ Qb,
                                                unsigned short* __restrict__ Vb) {
    const int row0  = blockIdx.y * 128;
    const int col0g = blockIdx.x * 128;
    const int seg   = col0g >> 10;
    const int col0  = col0g & 1023;
    const unsigned short* B = seg == 0 ? WKt : (seg == 1 ? WQt : WVt);
    unsigned short*       C = seg == 0 ? Kb  : (seg == 1 ? Qb  : Vb);
    const float alpha = (seg == 1) ? 0.06f : 1.0f;

    __shared__ unsigned short Asb[128 * 32];
    __shared__ unsigned short Bsb[128 * 32];

    const int t    = threadIdx.x;
    const int w    = t >> 6;
    const int lane = t & 63;
    const int wr   = (w >> 1) * 64;
    const int wc   = (w & 1) * 64;

    float4_t acc[4][4] = {};

    const int sr = lane >> 2;                               // row in chunk
    const int sk = (((lane & 3) ^ ((sr >> 1) & 3))) * 8;    // swizzled k-offset
    const int slot = ((lane >> 4) ^ ((lane >> 1) & 3)) * 8; // reader slot (elements)
    const int m  = lane & 15;

    for (int k0 = 0; k0 < M_DIM; k0 += 32) {
#pragma unroll
        for (int cc = 0; cc < 2; ++cc) {
            const int c = 2 * w + cc;
            const int rr = c * 16 + sr;
            gload16(&xb[(size_t)(row0 + rr) * M_DIM + k0 + sk], &Asb[c * 512]);
            gload16(&B[(size_t)(col0 + rr) * M_DIM + k0 + sk], &Bsb[c * 512]);
        }
        __syncthreads();
        short8 af[4], bf[4];
#pragma unroll
        for (int i = 0; i < 4; ++i)
            af[i] = *reinterpret_cast<const short8*>(&Asb[(wr + i * 16 + m) * 32 + slot]);
#pragma unroll
        for (int j = 0; j < 4; ++j)
            bf[j] = *reinterpret_cast<const short8*>(&Bsb[(wc + j * 16 + m) * 32 + slot]);
#pragma unroll
        for (int i = 0; i < 4; ++i)
#pragma unroll
            for (int j = 0; j < 4; ++j)
                acc[i][j] = __builtin_amdgcn_mfma_f32_16x16x32_bf16(af[i], bf[j], acc[i][j], 0, 0, 0);
        __syncthreads();
    }

    const int crow = row0 + wr + (lane >> 4) * 4;
    const int ccol = col0 + wc + m;
#pragma unroll
    for (int i = 0; i < 4; ++i)
#pragma unroll
        for (int j = 0; j < 4; ++j)
#pragma unroll
            for (int r = 0; r < 4; ++r)
                C[(size_t)(crow + i * 16 + r) * M_DIM + ccol + j * 16] = f2bf(alpha * acc[i][j][r]);
}

// ---------------------------------------------------------------------------
// logits = Q @ K^T, 128x128 tile, aperture tile-skip, fp32 out.
// ---------------------------------------------------------------------------
__global__ __launch_bounds__(256) void mfma_logits(const unsigned short* __restrict__ A,
                                                   const unsigned short* __restrict__ B,
                                                   float* __restrict__ Cf) {
    const int row0 = blockIdx.y * 128;
    const int col0 = blockIdx.x * 128;
    if (col0 + 127 <= row0 + APER) return; // fully masked tile

    __shared__ unsigned short Asb[128 * 32];
    __shared__ unsigned short Bsb[128 * 32];

    const int t    = threadIdx.x;
    const int w    = t >> 6;
    const int lane = t & 63;
    const int wr   = (w >> 1) * 64;
    const int wc   = (w & 1) * 64;

    float4_t acc[4][4] = {};

    const int sr = lane >> 2;
    const int sk = (((lane & 3) ^ ((sr >> 1) & 3))) * 8;
    const int slot = ((lane >> 4) ^ ((lane >> 1) & 3)) * 8;
    const int m  = lane & 15;

    for (int k0 = 0; k0 < M_DIM; k0 += 32) {
#pragma unroll
        for (int cc = 0; cc < 2; ++cc) {
            const int c = 2 * w + cc;
            const int rr = c * 16 + sr;
            gload16(&A[(size_t)(row0 + rr) * M_DIM + k0 + sk], &Asb[c * 512]);
            gload16(&B[(size_t)(col0 + rr) * M_DIM + k0 + sk], &Bsb[c * 512]);
        }
        __syncthreads();
        short8 af[4], bf[4];
#pragma unroll
        for (int i = 0; i < 4; ++i)
            af[i] = *reinterpret_cast<const short8*>(&Asb[(wr + i * 16 + m) * 32 + slot]);
#pragma unroll
        for (int j = 0; j < 4; ++j)
            bf[j] = *reinterpret_cast<const short8*>(&Bsb[(wc + j * 16 + m) * 32 + slot]);
#pragma unroll
        for (int i = 0; i < 4; ++i)
#pragma unroll
            for (int j = 0; j < 4; ++j)
                acc[i][j] = __builtin_amdgcn_mfma_f32_16x16x32_bf16(af[i], bf[j], acc[i][j], 0, 0, 0);
        __syncthreads();
    }

    const int crow = row0 + wr + (lane >> 4) * 4;
    const int ccol = col0 + wc + m;
#pragma unroll
    for (int i = 0; i < 4; ++i)
#pragma unroll
        for (int j = 0; j < 4; ++j)
#pragma unroll
            for (int r = 0; r < 4; ++r)
                Cf[(size_t)(crow + i * 16 + r) * N_TOK + ccol + j * 16] = acc[i][j][r];
}

// ---------------------------------------------------------------------------
// 64x128-tile NT GEMM (grid = (N/128, M/64)): C = A[MxK] @ B[NxK]^T.
// SKIP==2: A = att^T zero-k-block skip + heavy-strip-first dispatch order.
// ---------------------------------------------------------------------------
template <int SKIP>
__global__ __launch_bounds__(256) void mfma_nt64(const unsigned short* __restrict__ A,
                                                 const unsigned short* __restrict__ B,
                                                 float* __restrict__ Cf,
                                                 unsigned short* __restrict__ Cb,
                                                 int N, int K, float alpha) {
    const int by   = (SKIP == 2) ? (gridDim.y - 1 - blockIdx.y) : blockIdx.y;
    const int row0 = by * 64;
    const int col0 = blockIdx.x * 128;

    __shared__ unsigned short Asb[64 * 32];
    __shared__ unsigned short Bsb[128 * 32];

    const int t    = threadIdx.x;
    const int w    = t >> 6;
    const int lane = t & 63;
    const int wr   = (w >> 1) * 32;
    const int wc   = (w & 1) * 64;

    float4_t acc[2][4] = {};

    const int sr = lane >> 2;
    const int sk = (((lane & 3) ^ ((sr >> 1) & 3))) * 8;
    const int slot = ((lane >> 4) ^ ((lane >> 1) & 3)) * 8;
    const int m  = lane & 15;

    for (int k0 = 0; k0 < K; k0 += 32) {
        if (SKIP == 2) {
            if ((k0 > row0 + 63 - APER - 1) && (k0 + 31 < N_TOK - APER - 1)) continue;
        }
        {   // A: 4 chunks of 16 rows; wave w loads chunk w
            const int rr = w * 16 + sr;
            gload16(&A[(size_t)(row0 + rr) * K + k0 + sk], &Asb[w * 512]);
        }
#pragma unroll
        for (int cc = 0; cc < 2; ++cc) {
            const int c = 2 * w + cc;
            const int rr = c * 16 + sr;
            gload16(&B[(size_t)(col0 + rr) * K + k0 + sk], &Bsb[c * 512]);
        }
        __syncthreads();
        short8 af[2], bf[4];
#pragma unroll
        for (int i = 0; i < 2; ++i)
            af[i] = *reinterpret_cast<const short8*>(&Asb[(wr + i * 16 + m) * 32 + slot]);
#pragma unroll
        for (int j = 0; j < 4; ++j)
            bf[j] = *reinterpret_cast<const short8*>(&Bsb[(wc + j * 16 + m) * 32 + slot]);
#pragma unroll
        for (int i = 0; i < 2; ++i)
#pragma unroll
            for (int j = 0; j < 4; ++j)
                acc[i][j] = __builtin_amdgcn_mfma_f32_16x16x32_bf16(af[i], bf[j], acc[i][j], 0, 0, 0);
        __syncthreads();
    }

    const int crow = row0 + wr + (lane >> 4) * 4;
    const int ccol = col0 + wc + m;
#pragma unroll
    for (int i = 0; i < 2; ++i)
#pragma unroll
        for (int j = 0; j < 4; ++j)
#pragma unroll
            for (int r = 0; r < 4; ++r) {
                const float v = alpha * acc[i][j][r];
                const size_t idx = (size_t)(crow + i * 16 + r) * N + ccol + j * 16;
                if (Cf) Cf[idx] = v;
                if (Cb) Cb[idx] = f2bf(v);
            }
}

// ---------------------------------------------------------------------------
// In-place masked softmax, float4-vectorized.
// ---------------------------------------------------------------------------
__global__ __launch_bounds__(256) void softmax_mask(float* __restrict__ att) {
    const int i = blockIdx.x;
    const int t = threadIdx.x;
    float4* row4 = reinterpret_cast<float4*>(att + (size_t)i * N_TOK);
    const int jstart = i + APER + 1;

    if (jstart >= N_TOK) {
        const float u = 1.0f / (float)N_TOK;
        float4 uv; uv.x = uv.y = uv.z = uv.w = u;
        for (int q = t; q < N_TOK / 4; q += 256) row4[q] = uv;
        return;
    }

    __shared__ float sred[4];
    const int wid = t >> 6, lid = t & 63;
    const int q0 = jstart >> 2;

    // pass 1: row max over kept
    float lmax = -FMAXV;
    for (int q = q0 + t; q < N_TOK / 4; q += 256) {
        const float4 v = row4[q];
        const int j = q * 4;
        if (j >= jstart) {
            lmax = fmaxf(lmax, fmaxf(fmaxf(v.x, v.y), fmaxf(v.z, v.w)));
        } else {
            if (j + 1 >= jstart) lmax = fmaxf(lmax, v.y);
            if (j + 2 >= jstart) lmax = fmaxf(lmax, v.z);
            lmax = fmaxf(lmax, v.w); // j+3 >= jstart always in boundary quad
        }
    }
#pragma unroll
    for (int off = 32; off > 0; off >>= 1) lmax = fmaxf(lmax, __shfl_down(lmax, off, 64));
    if (lid == 0) sred[wid] = lmax;
    __syncthreads();
    const float rmax = fmaxf(fmaxf(sred[0], sred[1]), fmaxf(sred[2], sred[3]));
    __syncthreads();

    // pass 2: exp in place (masked lanes of boundary quad -> 0) + sum
    float lsum = 0.0f;
    for (int q = q0 + t; q < N_TOK / 4; q += 256) {
        float4 v = row4[q];
        const int j = q * 4;
        float4 e;
        e.x = (j + 0 >= jstart) ? __expf(v.x - rmax) : 0.0f;
        e.y = (j + 1 >= jstart) ? __expf(v.y - rmax) : 0.0f;
        e.z = (j + 2 >= jstart) ? __expf(v.z - rmax) : 0.0f;
        e.w = __expf(v.w - rmax);
        row4[q] = e;
        lsum += e.x + e.y + e.z + e.w;
    }
#pragma unroll
    for (int off = 32; off > 0; off >>= 1) lsum += __shfl_down(lsum, off, 64);
    if (lid == 0) sred[wid] = lsum;
    __syncthreads();
    const float inv = 1.0f / (sred[0] + sred[1] + sred[2] + sred[3]);

    // pass 3: zero masked quads, scale kept quads
    float4 z; z.x = z.y = z.z = z.w = 0.0f;
    for (int q = t; q < q0; q += 256) row4[q] = z;
    for (int q = q0 + t; q < N_TOK / 4; q += 256) {
        float4 v = row4[q];
        v.x *= inv; v.y *= inv; v.z *= inv; v.w *= inv;
        row4[q] = v;
    }
}

// ---------------------------------------------------------------------------
// att (fp32) -> attT (bf16), skipping all-zero tiles (write zeros, no read).
// ---------------------------------------------------------------------------
__global__ __launch_bounds__(256) void att_transpose(const float* __restrict__ src,
                                                     unsigned short* __restrict__ dst) {
    const int c0 = blockIdx.x * 32, r0 = blockIdx.y * 32;
    const int t = threadIdx.x;
    if ((c0 + 31 <= r0 + APER) && (r0 + 31 < N_TOK - APER - 1)) {
        const int rr = t >> 3;
        const int cc = (t & 7) * 4;
        ushort4 z; z.x = z.y = z.z = z.w = 0;
        *reinterpret_cast<ushort4*>(&dst[(size_t)(c0 + rr) * N_TOK + r0 + cc]) = z;
        return;
    }
    __shared__ unsigned short tile[32][33];
    const int tx = t & 31, ty = t >> 5;
#pragma unroll
    for (int i = ty; i < 32; i += 8)
        tile[i][tx] = f2bf(src[(size_t)(r0 + i) * N_TOK + c0 + tx]);
    __syncthreads();
#pragma unroll
    for (int i = ty; i < 32; i += 8)
        dst[(size_t)(c0 + i) * N_TOK + r0 + tx] = tile[tx][i];
}

extern "C" void kernel_launch(void* const* d_in, const int* in_sizes, int n_in,
                              void* d_out, int out_size, void* d_ws, size_t ws_size,
                              hipStream_t stream) {
    const float* x    = (const float*)d_in[0];
    const float* WK   = (const float*)d_in[1];
    const float* WQ   = (const float*)d_in[2];
    const float* WV   = (const float*)d_in[3];
    const float* Wout = (const float*)d_in[4];

    float* y   = (float*)d_out;                  // 4096 x 1024 fp32
    float* att = y + (size_t)N_TOK * M_DIM;      // 4096 x 4096 fp32

    unsigned short* p = (unsigned short*)d_ws;
    unsigned short* xb    = p; p += (size_t)N_TOK * M_DIM;  // 8 MB
    unsigned short* WKt   = p; p += (size_t)M_DIM * M_DIM;  // 2 MB
    unsigned short* WQt   = p; p += (size_t)M_DIM * M_DIM;
    unsigned short* WVt   = p; p += (size_t)M_DIM * M_DIM;
    unsigned short* Woutt = p; p += (size_t)M_DIM * M_DIM;
    unsigned short* Kb    = p; p += (size_t)N_TOK * M_DIM;  // 8 MB
    unsigned short* Qb    = p; p += (size_t)N_TOK * M_DIM;
    unsigned short* Vb    = p; p += (size_t)N_TOK * M_DIM;
    unsigned short* attT  = p; p += (size_t)N_TOK * N_TOK;  // 32 MB
    unsigned short* Vt    = xb;  // reuse: xb dead after QKV
    unsigned short* ytb   = Qb;  // reuse: Qb dead after logits

    const dim3 blk(256);

    cast_bf16<<<dim3((N_TOK * M_DIM) / 1024), blk, 0, stream>>>(x, xb, N_TOK * M_DIM);
    wtrans<<<dim3(M_DIM / 32, M_DIM / 32, 4), blk, 0, stream>>>(WK, WQ, WV, Wout,
                                                                WKt, WQt, WVt, Woutt);

    mfma_qkv<<<dim3(24, N_TOK / 128), blk, 0, stream>>>(xb, WKt, WQt, WVt, Kb, Qb, Vb);

    mfma_logits<<<dim3(N_TOK / 128, N_TOK / 128), blk, 0, stream>>>(Qb, Kb, att);

    softmax_mask<<<dim3(N_TOK), blk, 0, stream>>>(att);

    att_transpose<<<dim3(N_TOK / 32, N_TOK / 32), blk, 0, stream>>>(att, attT);
    transpose_bf16<<<dim3(M_DIM / 32, N_TOK / 32), blk, 0, stream>>>(Vb, Vt, N_TOK, M_DIM);

    mfma_nt64<2><<<dim3(M_DIM / 128, N_TOK / 64), blk, 0, stream>>>(attT, Vt, nullptr, ytb,
                                                                    M_DIM, N_TOK, 1.0f);
    mfma_nt64<0><<<dim3(M_DIM / 128, N_TOK / 64), blk, 0, stream>>>(ytb, Woutt, y, nullptr,
                                                                    M_DIM, M_DIM, 1.0f);
}

// Round 4
// 296.559 us; speedup vs baseline: 4.1862x; 1.0486x over previous
//
#include <hip/hip_runtime.h>
#include <cstdint>
#include <cstddef>

#define N_TOK 4096
#define M_DIM 1024
#define APER  256
constexpr float FMAXV = 3.4028235e38f;

typedef __attribute__((ext_vector_type(8))) short short8;
typedef __attribute__((ext_vector_type(4))) float float4_t;

__device__ __forceinline__ unsigned short f2bf(float x) {
    union { float f; uint32_t u; } v; v.f = x;
    uint32_t u = v.u;
    u += 0x7FFFu + ((u >> 16) & 1u);   // round-to-nearest-even
    return (unsigned short)(u >> 16);
}

__device__ __forceinline__ void gload16(const void* g, void* l) {
    __builtin_amdgcn_global_load_lds(
        (const __attribute__((address_space(1))) void*)g,
        (__attribute__((address_space(3))) void*)l, 16, 0, 0);
}

// ---------------------------------------------------------------------------
// cast fp32 -> bf16, same layout.
// ---------------------------------------------------------------------------
__global__ __launch_bounds__(256) void cast_bf16(const float* __restrict__ src,
                                                 unsigned short* __restrict__ dst, int n) {
    const int i = (blockIdx.x * 256 + threadIdx.x) * 4;
    if (i >= n) return;
    const float4 v = *reinterpret_cast<const float4*>(&src[i]);
    ushort4 o;
    o.x = f2bf(v.x); o.y = f2bf(v.y); o.z = f2bf(v.z); o.w = f2bf(v.w);
    *reinterpret_cast<ushort4*>(&dst[i]) = o;
}

// ---------------------------------------------------------------------------
// transpose+cast of 3 weight matrices (1024x1024 fp32 -> bf16^T)
// ---------------------------------------------------------------------------
__global__ __launch_bounds__(256) void wtrans3(const float* __restrict__ W0, const float* __restrict__ W1,
                                               const float* __restrict__ W2,
                                               unsigned short* __restrict__ D0, unsigned short* __restrict__ D1,
                                               unsigned short* __restrict__ D2) {
    const int z = blockIdx.z;
    const float* src = z == 0 ? W0 : (z == 1 ? W1 : W2);
    unsigned short* dst = z == 0 ? D0 : (z == 1 ? D1 : D2);
    __shared__ unsigned short tile[32][33];
    const int c0 = blockIdx.x * 32, r0 = blockIdx.y * 32;
    const int tx = threadIdx.x & 31, ty = threadIdx.x >> 5;
#pragma unroll
    for (int i = ty; i < 32; i += 8)
        tile[i][tx] = f2bf(src[(size_t)(r0 + i) * M_DIM + c0 + tx]);
    __syncthreads();
#pragma unroll
    for (int i = ty; i < 32; i += 8)
        dst[(size_t)(c0 + i) * M_DIM + r0 + tx] = tile[tx][i];
}

// transpose bf16 [R x C] -> bf16 [C x R]
__global__ __launch_bounds__(256) void transpose_bf16(const unsigned short* __restrict__ src,
                                                      unsigned short* __restrict__ dst,
                                                      int R, int C) {
    __shared__ unsigned short tile[32][33];
    const int c0 = blockIdx.x * 32, r0 = blockIdx.y * 32;
    const int tx = threadIdx.x & 31, ty = threadIdx.x >> 5;
#pragma unroll
    for (int i = ty; i < 32; i += 8)
        tile[i][tx] = src[(size_t)(r0 + i) * C + c0 + tx];
    __syncthreads();
#pragma unroll
    for (int i = ty; i < 32; i += 8)
        dst[(size_t)(c0 + i) * R + r0 + tx] = tile[tx][i];
}

// ---------------------------------------------------------------------------
// 64x64-tile NT GEMM: C[M x N] = alpha * A[M x K] @ B[N x K]^T.
// 4 waves, each 16x64 (1x4 MFMA 16x16x32). grid (N/64, M/64).
// SKIP==1: A = att^T zero-k-block skip + heavy-strip-first (reversed y).
// ---------------------------------------------------------------------------
template <int SKIP>
__global__ __launch_bounds__(256) void nt64sq(const unsigned short* __restrict__ A,
                                              const unsigned short* __restrict__ B,
                                              float* __restrict__ Cf,
                                              unsigned short* __restrict__ Cb,
                                              int N, int K, float alpha) {
    const int by   = (SKIP == 1) ? ((int)gridDim.y - 1 - (int)blockIdx.y) : (int)blockIdx.y;
    const int row0 = by * 64;
    const int col0 = blockIdx.x * 64;

    __shared__ unsigned short Asb[64 * 32];
    __shared__ unsigned short Bsb[64 * 32];

    const int t = threadIdx.x, w = t >> 6, lane = t & 63;
    float4_t acc[4] = {};

    const int sr   = lane >> 2;
    const int sk   = ((lane & 3) ^ ((sr >> 1) & 3)) * 8;
    const int m    = lane & 15;
    const int slot = ((lane >> 4) ^ ((m >> 1) & 3)) * 8;

    for (int k0 = 0; k0 < K; k0 += 32) {
        if (SKIP == 1) {
            if ((k0 > row0 + 63 - APER - 1) && (k0 + 31 < N_TOK - APER - 1)) continue;
        }
        const int rr = w * 16 + sr;
        gload16(&A[(size_t)(row0 + rr) * K + k0 + sk], &Asb[w * 512]);
        gload16(&B[(size_t)(col0 + rr) * K + k0 + sk], &Bsb[w * 512]);
        __syncthreads();
        const short8 af = *reinterpret_cast<const short8*>(&Asb[(w * 16 + m) * 32 + slot]);
        short8 bf[4];
#pragma unroll
        for (int j = 0; j < 4; ++j)
            bf[j] = *reinterpret_cast<const short8*>(&Bsb[(j * 16 + m) * 32 + slot]);
#pragma unroll
        for (int j = 0; j < 4; ++j)
            acc[j] = __builtin_amdgcn_mfma_f32_16x16x32_bf16(af, bf[j], acc[j], 0, 0, 0);
        __syncthreads();
    }

    const int crow = row0 + w * 16 + (lane >> 4) * 4;
    const int ccol = col0 + m;
#pragma unroll
    for (int j = 0; j < 4; ++j)
#pragma unroll
        for (int r = 0; r < 4; ++r) {
            const float v = alpha * acc[j][r];
            const size_t idx = (size_t)(crow + r) * N + ccol + j * 16;
            if (Cf) Cf[idx] = v;
            if (Cb) Cb[idx] = f2bf(v);
        }
}

// ---------------------------------------------------------------------------
// Fused QKV: seg 0: Kb = xb@WKt^T; seg 1: Qb = 0.06*xb@WQt^T; seg 2: VWb = xb@WVWt^T.
// 128x128 tile, BK=32, XOR-swizzled LDS. Grid (24, 32).
// ---------------------------------------------------------------------------
__global__ __launch_bounds__(256) void mfma_qkv(const unsigned short* __restrict__ xb,
                                                const unsigned short* __restrict__ WKt,
                                                const unsigned short* __restrict__ WQt,
                                                const unsigned short* __restrict__ WVWt,
                                                unsigned short* __restrict__ Kb,
                                                unsigned short* __restrict__ Qb,
                                                unsigned short* __restrict__ VWb) {
    const int row0  = blockIdx.y * 128;
    const int col0g = blockIdx.x * 128;
    const int seg   = col0g >> 10;
    const int col0  = col0g & 1023;
    const unsigned short* B = seg == 0 ? WKt : (seg == 1 ? WQt : WVWt);
    unsigned short*       C = seg == 0 ? Kb  : (seg == 1 ? Qb  : VWb);
    const float alpha = (seg == 1) ? 0.06f : 1.0f;

    __shared__ unsigned short Asb[128 * 32];
    __shared__ unsigned short Bsb[128 * 32];

    const int t = threadIdx.x, w = t >> 6, lane = t & 63;
    const int wr = (w >> 1) * 64, wc = (w & 1) * 64;

    float4_t acc[4][4] = {};

    const int sr   = lane >> 2;
    const int sk   = ((lane & 3) ^ ((sr >> 1) & 3)) * 8;
    const int m    = lane & 15;
    const int slot = ((lane >> 4) ^ ((m >> 1) & 3)) * 8;

    for (int k0 = 0; k0 < M_DIM; k0 += 32) {
#pragma unroll
        for (int cc = 0; cc < 2; ++cc) {
            const int c = 2 * w + cc;
            const int rr = c * 16 + sr;
            gload16(&xb[(size_t)(row0 + rr) * M_DIM + k0 + sk], &Asb[c * 512]);
            gload16(&B[(size_t)(col0 + rr) * M_DIM + k0 + sk], &Bsb[c * 512]);
        }
        __syncthreads();
        short8 af[4], bf[4];
#pragma unroll
        for (int i = 0; i < 4; ++i)
            af[i] = *reinterpret_cast<const short8*>(&Asb[(wr + i * 16 + m) * 32 + slot]);
#pragma unroll
        for (int j = 0; j < 4; ++j)
            bf[j] = *reinterpret_cast<const short8*>(&Bsb[(wc + j * 16 + m) * 32 + slot]);
#pragma unroll
        for (int i = 0; i < 4; ++i)
#pragma unroll
            for (int j = 0; j < 4; ++j)
                acc[i][j] = __builtin_amdgcn_mfma_f32_16x16x32_bf16(af[i], bf[j], acc[i][j], 0, 0, 0);
        __syncthreads();
    }

    const int crow = row0 + wr + (lane >> 4) * 4;
    const int ccol = col0 + wc + m;
#pragma unroll
    for (int i = 0; i < 4; ++i)
#pragma unroll
        for (int j = 0; j < 4; ++j)
#pragma unroll
            for (int r = 0; r < 4; ++r)
                C[(size_t)(crow + i * 16 + r) * M_DIM + ccol + j * 16] = f2bf(alpha * acc[i][j][r]);
}

// ---------------------------------------------------------------------------
// logits+exp: att[r][c] = exp(Q[r]·K[c]) for non-skipped tiles; atomic per-row
// sums of KEPT (c > r+APER) entries into rowsum. Aperture tile-skip.
// ---------------------------------------------------------------------------
__global__ __launch_bounds__(256) void mfma_logits_exp(const unsigned short* __restrict__ A,
                                                       const unsigned short* __restrict__ B,
                                                       float* __restrict__ att,
                                                       float* __restrict__ rowsum) {
    const int row0 = blockIdx.y * 128;
    const int col0 = blockIdx.x * 128;
    if (col0 + 127 <= row0 + APER) return; // fully masked tile

    __shared__ unsigned short Asb[128 * 32];
    __shared__ unsigned short Bsb[128 * 32];

    const int t = threadIdx.x, w = t >> 6, lane = t & 63;
    const int wr = (w >> 1) * 64, wc = (w & 1) * 64;

    float4_t acc[4][4] = {};

    const int sr   = lane >> 2;
    const int sk   = ((lane & 3) ^ ((sr >> 1) & 3)) * 8;
    const int m    = lane & 15;
    const int slot = ((lane >> 4) ^ ((m >> 1) & 3)) * 8;

    for (int k0 = 0; k0 < M_DIM; k0 += 32) {
#pragma unroll
        for (int cc = 0; cc < 2; ++cc) {
            const int c = 2 * w + cc;
            const int rr = c * 16 + sr;
            gload16(&A[(size_t)(row0 + rr) * M_DIM + k0 + sk], &Asb[c * 512]);
            gload16(&B[(size_t)(col0 + rr) * M_DIM + k0 + sk], &Bsb[c * 512]);
        }
        __syncthreads();
        short8 af[4], bf[4];
#pragma unroll
        for (int i = 0; i < 4; ++i)
            af[i] = *reinterpret_cast<const short8*>(&Asb[(wr + i * 16 + m) * 32 + slot]);
#pragma unroll
        for (int j = 0; j < 4; ++j)
            bf[j] = *reinterpret_cast<const short8*>(&Bsb[(wc + j * 16 + m) * 32 + slot]);
#pragma unroll
        for (int i = 0; i < 4; ++i)
#pragma unroll
            for (int j = 0; j < 4; ++j)
                acc[i][j] = __builtin_amdgcn_mfma_f32_16x16x32_bf16(af[i], bf[j], acc[i][j], 0, 0, 0);
        __syncthreads();
    }

    // epilogue: exp + write + masked row-sum (shfl reduce over the 16 lanes of a row)
    const int crow = row0 + wr + (lane >> 4) * 4;
    const int ccol = col0 + wc + m;
#pragma unroll
    for (int i = 0; i < 4; ++i) {
#pragma unroll
        for (int r = 0; r < 4; ++r) {
            const int gr = crow + i * 16 + r;
            float partial = 0.0f;
#pragma unroll
            for (int j = 0; j < 4; ++j) {
                const int gc = ccol + j * 16;
                const float e = __expf(acc[i][j][r]);
                att[(size_t)gr * N_TOK + gc] = e;
                if (gc > gr + APER) partial += e;
            }
            partial += __shfl_xor(partial, 1, 64);
            partial += __shfl_xor(partial, 2, 64);
            partial += __shfl_xor(partial, 4, 64);
            partial += __shfl_xor(partial, 8, 64);
            if (m == 0) atomicAdd(&rowsum[gr], partial);
        }
    }
}

// ---------------------------------------------------------------------------
// zero the 4096-float rowsum buffer
// ---------------------------------------------------------------------------
__global__ __launch_bounds__(256) void zero_rowsum(float* __restrict__ rowsum) {
    const int i = (blockIdx.x * 256 + threadIdx.x) * 4;
    float4 z; z.x = z.y = z.z = z.w = 0.0f;
    *reinterpret_cast<float4*>(&rowsum[i]) = z;
}

// ---------------------------------------------------------------------------
// normalize att in place: kept (j > i+APER) scaled by 1/rowsum[i]; masked -> 0;
// rows i >= 3839 -> uniform 1/N.
// ---------------------------------------------------------------------------
__global__ __launch_bounds__(256) void normalize_att(float* __restrict__ att,
                                                     const float* __restrict__ rowsum) {
    const int i = blockIdx.x;
    const int t = threadIdx.x;
    float4* row4 = reinterpret_cast<float4*>(att + (size_t)i * N_TOK);
    const int jstart = i + APER + 1;

    if (jstart >= N_TOK) {
        const float u = 1.0f / (float)N_TOK;
        float4 uv; uv.x = uv.y = uv.z = uv.w = u;
        for (int q = t; q < N_TOK / 4; q += 256) row4[q] = uv;
        return;
    }

    const float inv = 1.0f / rowsum[i];
    const int q0 = jstart >> 2;
    float4 z; z.x = z.y = z.z = z.w = 0.0f;
    for (int q = t; q < q0; q += 256) row4[q] = z;
    for (int q = q0 + t; q < N_TOK / 4; q += 256) {
        float4 v = row4[q];
        const int j = q * 4;
        v.x = (j + 0 >= jstart) ? v.x * inv : 0.0f;
        v.y = (j + 1 >= jstart) ? v.y * inv : 0.0f;
        v.z = (j + 2 >= jstart) ? v.z * inv : 0.0f;
        v.w = v.w * inv;
        row4[q] = v;
    }
}

// ---------------------------------------------------------------------------
// att (fp32, normalized) -> attT (bf16), skipping reads of all-zero tiles.
// ---------------------------------------------------------------------------
__global__ __launch_bounds__(256) void att_transpose(const float* __restrict__ src,
                                                     unsigned short* __restrict__ dst) {
    const int c0 = blockIdx.x * 32, r0 = blockIdx.y * 32;
    const int t = threadIdx.x;
    if ((c0 + 31 <= r0 + APER) && (r0 + 31 < N_TOK - APER - 1)) {
        const int rr = t >> 3;
        const int cc = (t & 7) * 4;
        ushort4 z; z.x = z.y = z.z = z.w = 0;
        *reinterpret_cast<ushort4*>(&dst[(size_t)(c0 + rr) * N_TOK + r0 + cc]) = z;
        return;
    }
    __shared__ unsigned short tile[32][33];
    const int tx = t & 31, ty = t >> 5;
#pragma unroll
    for (int i = ty; i < 32; i += 8)
        tile[i][tx] = f2bf(src[(size_t)(r0 + i) * N_TOK + c0 + tx]);
    __syncthreads();
#pragma unroll
    for (int i = ty; i < 32; i += 8)
        dst[(size_t)(c0 + i) * N_TOK + r0 + tx] = tile[tx][i];
}

extern "C" void kernel_launch(void* const* d_in, const int* in_sizes, int n_in,
                              void* d_out, int out_size, void* d_ws, size_t ws_size,
                              hipStream_t stream) {
    const float* x    = (const float*)d_in[0];
    const float* WK   = (const float*)d_in[1];
    const float* WQ   = (const float*)d_in[2];
    const float* WV   = (const float*)d_in[3];
    const float* Wout = (const float*)d_in[4];

    float* y   = (float*)d_out;                  // 4096 x 1024 fp32
    float* att = y + (size_t)N_TOK * M_DIM;      // 4096 x 4096 fp32

    // ws layout (ushort elements); 1M = 1<<20 elems = 2 MB
    unsigned short* base = (unsigned short*)d_ws;
    const size_t MEG = 1u << 20;
    unsigned short* xb    = base;             // [0,  4M)  x bf16 / later VWt
    unsigned short* WKt   = base + 4  * MEG;  // [4M, 5M)
    unsigned short* WQt   = base + 5  * MEG;  // [5M, 6M)
    unsigned short* Woutt = base + 6  * MEG;  // [6M, 7M)
    unsigned short* WVb   = base + 7  * MEG;  // [7M, 8M)
    unsigned short* WVWt  = base + 8  * MEG;  // [8M, 9M)
    unsigned short* Kb    = base + 9  * MEG;  // [9M, 13M)
    unsigned short* Qb    = base + 13 * MEG;  // [13M,17M)
    unsigned short* VWb   = base + 17 * MEG;  // [17M,21M)
    unsigned short* attT  = base + 4  * MEG;  // [4M, 20M) — aliases weights/Kb/Qb/VWb (all dead)
    float*          rowsum = (float*)(base + 20 * MEG); // 16 KB, after attT region
    unsigned short* VWt   = xb;               // aliases xb (dead after QKV)

    const dim3 blk(256);

    // 1) casts / transposes of inputs
    cast_bf16<<<dim3((N_TOK * M_DIM) / 1024), blk, 0, stream>>>(x, xb, N_TOK * M_DIM);
    cast_bf16<<<dim3((M_DIM * M_DIM) / 1024), blk, 0, stream>>>(WV, WVb, M_DIM * M_DIM);
    wtrans3<<<dim3(M_DIM / 32, M_DIM / 32, 3), blk, 0, stream>>>(WK, WQ, Wout, WKt, WQt, Woutt);

    // 2) WVW^T = Wout^T @ WV^T  (so VW-segment of QKV computes x@WV@Wout)
    nt64sq<0><<<dim3(M_DIM / 64, M_DIM / 64), blk, 0, stream>>>(Woutt, WVb, nullptr, WVWt,
                                                                M_DIM, M_DIM, 1.0f);

    // 3) fused K/Q/VW projections
    mfma_qkv<<<dim3(24, N_TOK / 128), blk, 0, stream>>>(xb, WKt, WQt, WVWt, Kb, Qb, VWb);

    // 4) VW^T for the final NT GEMM
    transpose_bf16<<<dim3(M_DIM / 32, N_TOK / 32), blk, 0, stream>>>(VWb, VWt, N_TOK, M_DIM);

    // 5) logits + exp + atomic row-sums
    zero_rowsum<<<dim3(4), blk, 0, stream>>>(rowsum);
    mfma_logits_exp<<<dim3(N_TOK / 128, N_TOK / 128), blk, 0, stream>>>(Qb, Kb, att, rowsum);

    // 6) normalize att (graded fp32 output)
    normalize_att<<<dim3(N_TOK), blk, 0, stream>>>(att, rowsum);

    // 7) att^T in bf16
    att_transpose<<<dim3(N_TOK / 32, N_TOK / 32), blk, 0, stream>>>(att, attT);

    // 8) y = att^T @ VW  (fp32 out, zero-k skip, heavy-first)
    nt64sq<1><<<dim3(M_DIM / 64, N_TOK / 64), blk, 0, stream>>>(attT, VWt, y, nullptr,
                                                                M_DIM, N_TOK, 1.0f);
}

// Round 6
// 290.149 us; speedup vs baseline: 4.2787x; 1.0221x over previous
//
#include <hip/hip_runtime.h>
#include <cstdint>
#include <cstddef>

#define N_TOK 4096
#define M_DIM 1024
#define APER  256
#define UNIF_START 3839   // rows >= this have no kept entries -> uniform 1/N

typedef __attribute__((ext_vector_type(8))) short short8;
typedef __attribute__((ext_vector_type(4))) float float4_t;

__device__ __forceinline__ unsigned short f2bf(float x) {
    union { float f; uint32_t u; } v; v.f = x;
    uint32_t u = v.u;
    u += 0x7FFFu + ((u >> 16) & 1u);   // round-to-nearest-even
    return (unsigned short)(u >> 16);
}

__device__ __forceinline__ void gload16(const void* g, void* l) {
    __builtin_amdgcn_global_load_lds(
        (const __attribute__((address_space(1))) void*)g,
        (__attribute__((address_space(3))) void*)l, 16, 0, 0);
}

// ---------------------------------------------------------------------------
// cast fp32 -> bf16, same layout.
// ---------------------------------------------------------------------------
__global__ __launch_bounds__(256) void cast_bf16(const float* __restrict__ src,
                                                 unsigned short* __restrict__ dst, int n) {
    const int i = (blockIdx.x * 256 + threadIdx.x) * 4;
    if (i >= n) return;
    const float4 v = *reinterpret_cast<const float4*>(&src[i]);
    ushort4 o;
    o.x = f2bf(v.x); o.y = f2bf(v.y); o.z = f2bf(v.z); o.w = f2bf(v.w);
    *reinterpret_cast<ushort4*>(&dst[i]) = o;
}

// ---------------------------------------------------------------------------
// transpose+cast of 3 weight matrices (1024x1024 fp32 -> bf16^T)
// ---------------------------------------------------------------------------
__global__ __launch_bounds__(256) void wtrans3(const float* __restrict__ W0, const float* __restrict__ W1,
                                               const float* __restrict__ W2,
                                               unsigned short* __restrict__ D0, unsigned short* __restrict__ D1,
                                               unsigned short* __restrict__ D2) {
    const int z = blockIdx.z;
    const float* src = z == 0 ? W0 : (z == 1 ? W1 : W2);
    unsigned short* dst = z == 0 ? D0 : (z == 1 ? D1 : D2);
    __shared__ unsigned short tile[32][33];
    const int c0 = blockIdx.x * 32, r0 = blockIdx.y * 32;
    const int tx = threadIdx.x & 31, ty = threadIdx.x >> 5;
#pragma unroll
    for (int i = ty; i < 32; i += 8)
        tile[i][tx] = f2bf(src[(size_t)(r0 + i) * M_DIM + c0 + tx]);
    __syncthreads();
#pragma unroll
    for (int i = ty; i < 32; i += 8)
        dst[(size_t)(c0 + i) * M_DIM + r0 + tx] = tile[tx][i];
}

// transpose bf16 [R x C] -> bf16 [C x R]
__global__ __launch_bounds__(256) void transpose_bf16(const unsigned short* __restrict__ src,
                                                      unsigned short* __restrict__ dst,
                                                      int R, int C) {
    __shared__ unsigned short tile[32][33];
    const int c0 = blockIdx.x * 32, r0 = blockIdx.y * 32;
    const int tx = threadIdx.x & 31, ty = threadIdx.x >> 5;
#pragma unroll
    for (int i = ty; i < 32; i += 8)
        tile[i][tx] = src[(size_t)(r0 + i) * C + c0 + tx];
    __syncthreads();
#pragma unroll
    for (int i = ty; i < 32; i += 8)
        dst[(size_t)(c0 + i) * R + r0 + tx] = tile[tx][i];
}

// ---------------------------------------------------------------------------
// 64x64-tile NT GEMM (BK=32), proven R4 core. SKIP==1: att^T zero-k skip.
// ---------------------------------------------------------------------------
template <int SKIP>
__global__ __launch_bounds__(256) void nt64sq(const unsigned short* __restrict__ A,
                                              const unsigned short* __restrict__ B,
                                              float* __restrict__ Cf,
                                              unsigned short* __restrict__ Cb,
                                              int N, int K) {
    const int by   = (SKIP == 1) ? ((int)gridDim.y - 1 - (int)blockIdx.y) : (int)blockIdx.y;
    const int row0 = by * 64;
    const int col0 = blockIdx.x * 64;

    __shared__ unsigned short Asb[64 * 32];
    __shared__ unsigned short Bsb[64 * 32];

    const int t = threadIdx.x, w = t >> 6, lane = t & 63;
    float4_t acc[4] = {};

    const int sr   = lane >> 2;
    const int sk   = ((lane & 3) ^ ((sr >> 1) & 3)) * 8;
    const int m    = lane & 15;
    const int slot = ((lane >> 4) ^ ((m >> 1) & 3)) * 8;

    for (int k0 = 0; k0 < K; k0 += 32) {
        if (SKIP == 1) {
            if ((k0 > row0 + 63 - APER - 1) && (k0 + 31 < UNIF_START)) continue;
        }
        const int rr = w * 16 + sr;
        gload16(&A[(size_t)(row0 + rr) * K + k0 + sk], &Asb[w * 512]);
        gload16(&B[(size_t)(col0 + rr) * K + k0 + sk], &Bsb[w * 512]);
        __syncthreads();
        const short8 af = *reinterpret_cast<const short8*>(&Asb[(w * 16 + m) * 32 + slot]);
        short8 bf[4];
#pragma unroll
        for (int j = 0; j < 4; ++j)
            bf[j] = *reinterpret_cast<const short8*>(&Bsb[(j * 16 + m) * 32 + slot]);
#pragma unroll
        for (int j = 0; j < 4; ++j)
            acc[j] = __builtin_amdgcn_mfma_f32_16x16x32_bf16(af, bf[j], acc[j], 0, 0, 0);
        __syncthreads();
    }

    const int crow = row0 + w * 16 + (lane >> 4) * 4;
    const int ccol = col0 + m;
#pragma unroll
    for (int j = 0; j < 4; ++j)
#pragma unroll
        for (int r = 0; r < 4; ++r) {
            const float v = acc[j][r];
            const size_t idx = (size_t)(crow + r) * N + ccol + j * 16;
            if (Cf) Cf[idx] = v;
            if (Cb) Cb[idx] = f2bf(v);
        }
}

// ---------------------------------------------------------------------------
// Fused QKV (R4-proven BK=32 core): seg0 Kb, seg1 Qb (x0.06), seg2 VWb.
// ---------------------------------------------------------------------------
__global__ __launch_bounds__(256) void mfma_qkv(const unsigned short* __restrict__ xb,
                                                const unsigned short* __restrict__ WKt,
                                                const unsigned short* __restrict__ WQt,
                                                const unsigned short* __restrict__ WVWt,
                                                unsigned short* __restrict__ Kb,
                                                unsigned short* __restrict__ Qb,
                                                unsigned short* __restrict__ VWb) {
    const int row0  = blockIdx.y * 128;
    const int col0g = blockIdx.x * 128;
    const int seg   = col0g >> 10;
    const int col0  = col0g & 1023;
    const unsigned short* B = seg == 0 ? WKt : (seg == 1 ? WQt : WVWt);
    unsigned short*       C = seg == 0 ? Kb  : (seg == 1 ? Qb  : VWb);
    const float alpha = (seg == 1) ? 0.06f : 1.0f;

    __shared__ unsigned short Asb[128 * 32];
    __shared__ unsigned short Bsb[128 * 32];

    const int t = threadIdx.x, w = t >> 6, lane = t & 63;
    const int wr = (w >> 1) * 64, wc = (w & 1) * 64;

    float4_t acc[4][4] = {};

    const int sr   = lane >> 2;
    const int sk   = ((lane & 3) ^ ((sr >> 1) & 3)) * 8;
    const int m    = lane & 15;
    const int slot = ((lane >> 4) ^ ((m >> 1) & 3)) * 8;

    for (int k0 = 0; k0 < M_DIM; k0 += 32) {
#pragma unroll
        for (int cc = 0; cc < 2; ++cc) {
            const int c = 2 * w + cc;
            const int rr = c * 16 + sr;
            gload16(&xb[(size_t)(row0 + rr) * M_DIM + k0 + sk], &Asb[c * 512]);
            gload16(&B[(size_t)(col0 + rr) * M_DIM + k0 + sk], &Bsb[c * 512]);
        }
        __syncthreads();
        short8 af[4], bf[4];
#pragma unroll
        for (int i = 0; i < 4; ++i)
            af[i] = *reinterpret_cast<const short8*>(&Asb[(wr + i * 16 + m) * 32 + slot]);
#pragma unroll
        for (int j = 0; j < 4; ++j)
            bf[j] = *reinterpret_cast<const short8*>(&Bsb[(wc + j * 16 + m) * 32 + slot]);
#pragma unroll
        for (int i = 0; i < 4; ++i)
#pragma unroll
            for (int j = 0; j < 4; ++j)
                acc[i][j] = __builtin_amdgcn_mfma_f32_16x16x32_bf16(af[i], bf[j], acc[i][j], 0, 0, 0);
        __syncthreads();
    }

    const int crow = row0 + wr + (lane >> 4) * 4;
    const int ccol = col0 + wc + m;
#pragma unroll
    for (int i = 0; i < 4; ++i)
#pragma unroll
        for (int j = 0; j < 4; ++j)
#pragma unroll
            for (int r = 0; r < 4; ++r)
                C[(size_t)(crow + i * 16 + r) * M_DIM + ccol + j * 16] = f2bf(alpha * acc[i][j][r]);
}

// ---------------------------------------------------------------------------
// logits (R4-proven BK=32 core) with masked epilogue: att = E where
// masked->0, uniform rows->1, kept->exp(logit). Atomic rowsums (kept, rows
// < UNIF_START only).
// ---------------------------------------------------------------------------
__global__ __launch_bounds__(256) void mfma_logits_exp(const unsigned short* __restrict__ A,
                                                       const unsigned short* __restrict__ B,
                                                       float* __restrict__ att,
                                                       float* __restrict__ rowsum) {
    const int row0 = blockIdx.y * 128;
    const int col0 = blockIdx.x * 128;
    if (col0 + 127 <= row0 + APER) return; // fully masked tile: never computed

    __shared__ unsigned short Asb[128 * 32];
    __shared__ unsigned short Bsb[128 * 32];

    const int t = threadIdx.x, w = t >> 6, lane = t & 63;
    const int wr = (w >> 1) * 64, wc = (w & 1) * 64;

    float4_t acc[4][4] = {};

    const int sr   = lane >> 2;
    const int sk   = ((lane & 3) ^ ((sr >> 1) & 3)) * 8;
    const int m    = lane & 15;
    const int slot = ((lane >> 4) ^ ((m >> 1) & 3)) * 8;

    for (int k0 = 0; k0 < M_DIM; k0 += 32) {
#pragma unroll
        for (int cc = 0; cc < 2; ++cc) {
            const int c = 2 * w + cc;
            const int rr = c * 16 + sr;
            gload16(&A[(size_t)(row0 + rr) * M_DIM + k0 + sk], &Asb[c * 512]);
            gload16(&B[(size_t)(col0 + rr) * M_DIM + k0 + sk], &Bsb[c * 512]);
        }
        __syncthreads();
        short8 af[4], bf[4];
#pragma unroll
        for (int i = 0; i < 4; ++i)
            af[i] = *reinterpret_cast<const short8*>(&Asb[(wr + i * 16 + m) * 32 + slot]);
#pragma unroll
        for (int j = 0; j < 4; ++j)
            bf[j] = *reinterpret_cast<const short8*>(&Bsb[(wc + j * 16 + m) * 32 + slot]);
#pragma unroll
        for (int i = 0; i < 4; ++i)
#pragma unroll
            for (int j = 0; j < 4; ++j)
                acc[i][j] = __builtin_amdgcn_mfma_f32_16x16x32_bf16(af[i], bf[j], acc[i][j], 0, 0, 0);
        __syncthreads();
    }

    const int crow = row0 + wr + (lane >> 4) * 4;
    const int ccol = col0 + wc + m;
#pragma unroll
    for (int i = 0; i < 4; ++i) {
#pragma unroll
        for (int r = 0; r < 4; ++r) {
            const int gr = crow + i * 16 + r;
            float partial = 0.0f;
#pragma unroll
            for (int j = 0; j < 4; ++j) {
                const int gc = ccol + j * 16;
                float val;
                if (gr >= UNIF_START) {
                    val = 1.0f;
                } else if (gc > gr + APER) {
                    val = __expf(acc[i][j][r]);
                    partial += val;
                } else {
                    val = 0.0f;
                }
                att[(size_t)gr * N_TOK + gc] = val;
            }
            partial += __shfl_xor(partial, 1, 64);
            partial += __shfl_xor(partial, 2, 64);
            partial += __shfl_xor(partial, 4, 64);
            partial += __shfl_xor(partial, 8, 64);
            if (m == 0 && gr < UNIF_START) atomicAdd(&rowsum[gr], partial);
        }
    }
}

// ---------------------------------------------------------------------------
// rowsum init: uniform rows start at exactly 4096 (E=1 for all cols).
// ---------------------------------------------------------------------------
__global__ __launch_bounds__(256) void init_rowsum(float* __restrict__ rowsum) {
    const int i = blockIdx.x * 256 + threadIdx.x;
    if (i < N_TOK) rowsum[i] = (i >= UNIF_START) ? (float)N_TOK : 0.0f;
}

// ---------------------------------------------------------------------------
// finalize: att = E * inv (in place, fp32) + attT = bf16(att)^T.
// 64x64 tiles; trivial tiles (all masked/uniform) take a no-read fast path.
// Coverage: slow-path tiles (j0-i0 >= 256) always lie in logits-computed
// 128-tiles (col0-row0 >= 192 > 129), so E is always written there.
// ---------------------------------------------------------------------------
__global__ __launch_bounds__(256) void finalize_att(float* __restrict__ att,
                                                    unsigned short* __restrict__ attT,
                                                    const float* __restrict__ rowsum) {
    const int j0 = blockIdx.x * 64, i0 = blockIdx.y * 64;
    const int t = threadIdx.x;
    const int rl = t >> 4;             // 0..15
    const int c4 = (t & 15) * 4;       // 0,4,..,60
    const float u = 1.0f / (float)N_TOK;

    if (j0 + 63 <= i0 + APER) {        // trivial: masked rows -> 0, uniform -> u
#pragma unroll
        for (int s = 0; s < 4; ++s) {
            const int i = i0 + rl + 16 * s;
            const float val = (i >= UNIF_START) ? u : 0.0f;
            float4 v; v.x = v.y = v.z = v.w = val;
            *reinterpret_cast<float4*>(&att[(size_t)i * N_TOK + j0 + c4]) = v;
        }
        const unsigned short bu = f2bf(u);
#pragma unroll
        for (int s = 0; s < 4; ++s) {
            const int j = j0 + rl + 16 * s;
            ushort4 o;
            o.x = (i0 + c4 + 0 >= UNIF_START) ? bu : 0;
            o.y = (i0 + c4 + 1 >= UNIF_START) ? bu : 0;
            o.z = (i0 + c4 + 2 >= UNIF_START) ? bu : 0;
            o.w = (i0 + c4 + 3 >= UNIF_START) ? bu : 0;
            *reinterpret_cast<ushort4*>(&attT[(size_t)j * N_TOK + i0 + c4]) = o;
        }
        return;
    }

    __shared__ unsigned short tile[64][72];
#pragma unroll
    for (int s = 0; s < 4; ++s) {
        const int il = rl + 16 * s;
        const int i  = i0 + il;
        const float inv = 1.0f / rowsum[i];
        float4 v = *reinterpret_cast<const float4*>(&att[(size_t)i * N_TOK + j0 + c4]);
        v.x *= inv; v.y *= inv; v.z *= inv; v.w *= inv;
        *reinterpret_cast<float4*>(&att[(size_t)i * N_TOK + j0 + c4]) = v;
        ushort4 b;
        b.x = f2bf(v.x); b.y = f2bf(v.y); b.z = f2bf(v.z); b.w = f2bf(v.w);
        *reinterpret_cast<ushort4*>(&tile[il][c4]) = b;
    }
    __syncthreads();
#pragma unroll
    for (int s = 0; s < 4; ++s) {
        const int jl = rl + 16 * s;
        ushort4 o;
        o.x = tile[c4 + 0][jl];
        o.y = tile[c4 + 1][jl];
        o.z = tile[c4 + 2][jl];
        o.w = tile[c4 + 3][jl];
        *reinterpret_cast<ushort4*>(&attT[(size_t)(j0 + jl) * N_TOK + i0 + c4]) = o;
    }
}

extern "C" void kernel_launch(void* const* d_in, const int* in_sizes, int n_in,
                              void* d_out, int out_size, void* d_ws, size_t ws_size,
                              hipStream_t stream) {
    const float* x    = (const float*)d_in[0];
    const float* WK   = (const float*)d_in[1];
    const float* WQ   = (const float*)d_in[2];
    const float* WV   = (const float*)d_in[3];
    const float* Wout = (const float*)d_in[4];

    float* y   = (float*)d_out;                  // 4096 x 1024 fp32
    float* att = y + (size_t)N_TOK * M_DIM;      // 4096 x 4096 fp32 (E, then normalized)

    // R4-proven ws layout (ushort elements); 1 MEG = 2 MB
    unsigned short* base = (unsigned short*)d_ws;
    const size_t MEG = 1u << 20;
    unsigned short* xb    = base;             // [0,4)   x bf16; later VWt
    unsigned short* WKt   = base + 4  * MEG;  // [4,5)
    unsigned short* WQt   = base + 5  * MEG;  // [5,6)
    unsigned short* Woutt = base + 6  * MEG;  // [6,7)
    unsigned short* WVb   = base + 7  * MEG;  // [7,8)
    unsigned short* WVWt  = base + 8  * MEG;  // [8,9)
    unsigned short* Kb    = base + 9  * MEG;  // [9,13)
    unsigned short* Qb    = base + 13 * MEG;  // [13,17)
    unsigned short* VWb   = base + 17 * MEG;  // [17,21)
    unsigned short* attT  = base + 4  * MEG;  // [4,20) overlays dead wgt/Kb/Qb/VWb[0..3M)
    float*          rowsum = (float*)(base + 20 * MEG); // 16 KB (after VWb read)
    unsigned short* VWt   = xb;               // [0,4) overlays dead xb

    const dim3 blk(256);

    // 1) input casts / transposes
    cast_bf16<<<dim3((N_TOK * M_DIM) / 1024), blk, 0, stream>>>(x, xb, N_TOK * M_DIM);
    cast_bf16<<<dim3((M_DIM * M_DIM) / 1024), blk, 0, stream>>>(WV, WVb, M_DIM * M_DIM);
    wtrans3<<<dim3(M_DIM / 32, M_DIM / 32, 3), blk, 0, stream>>>(WK, WQ, Wout, WKt, WQt, Woutt);

    // 2) WVW^T = Wout^T @ WV^T  (folds Wout into the V projection)
    nt64sq<0><<<dim3(M_DIM / 64, M_DIM / 64), blk, 0, stream>>>(Woutt, WVb, nullptr, WVWt,
                                                                M_DIM, M_DIM);

    // 3) fused K/Q/VW projections
    mfma_qkv<<<dim3(24, N_TOK / 128), blk, 0, stream>>>(xb, WKt, WQt, WVWt, Kb, Qb, VWb);

    // 4) VW^T (xb region is dead now)
    transpose_bf16<<<dim3(M_DIM / 32, N_TOK / 32), blk, 0, stream>>>(VWb, VWt, N_TOK, M_DIM);

    // 5) logits -> masked exp E + row sums
    init_rowsum<<<dim3(N_TOK / 256), blk, 0, stream>>>(rowsum);
    mfma_logits_exp<<<dim3(N_TOK / 128, N_TOK / 128), blk, 0, stream>>>(Qb, Kb, att, rowsum);

    // 6) normalize att in place + build attT (bf16), fused
    finalize_att<<<dim3(N_TOK / 64, N_TOK / 64), blk, 0, stream>>>(att, attT, rowsum);

    // 7) y = att^T @ VW  (zero-k skip, heavy strips first)
    nt64sq<1><<<dim3(M_DIM / 64, N_TOK / 64), blk, 0, stream>>>(attT, VWt, y, nullptr,
                                                                M_DIM, N_TOK);
}